// Round 8
// baseline (382.975 us; speedup 1.0000x reference)
//
#include <hip/hip_runtime.h>
#include <hip/hip_fp16.h>

// RoIAlign3D: features (B=2, C=256, 64,64,64) f32, proposals (B=2, N=512, 6) f32
// out: (B*N, C, 7, 7, 7) f32
//
// kernel1: bucket 3584 (roi,iz) entries per batch by z0=floor(gz) into CSR +
//   32 B record {x1p,sx,y1p,sy,wz,out_off}.
// kernel2: block = slice (b,c), 1024 thr, 4-plane LDS ring over z.
//   Packed-f16 pair slots: slot(y,x) = {h[x],h[x+1]} -> one b32 read = both
//   x-corners (4 LDS reads/point).
//   TWO-step-deep plane pipeline: at step z issue load of plane z+4, LDS-write
//   plane z+2 (loaded at z-2). 32 KB in flight per block -> feature stream is
//   BW-limited, not latency-limited. Non-temporal output stores keep L2/L3
//   for the feature stream.
// Coords in [0,63): floor <= 62, +1 <= 63 -> no clamping needed.

#define B_      2
#define C_      256
#define N_      512
#define NENT    (N_ * 7)
#define SP      66                  // slots per row (64 used + 2 pad)
#define PLANE_S (64 * SP)           // 4224 u32 slots per plane
#define THREADS 1024
#define GROUPS  20                  // 20*49 = 980 active lanes
#define REC_F_BASE 128
#define WS_NEEDED ((size_t)REC_F_BASE * 4 + (size_t)B_ * NENT * 8 * 4)

typedef _Float16 h2v __attribute__((ext_vector_type(2)));

__device__ __forceinline__ float gcoord(float lo, float hi, int i) {
    return lo + (hi - lo) * (1.0f / 6.0f) * (float)i;
}

__device__ __forceinline__ uint32_t pkrtz(float a, float b) {
    auto h = __builtin_amdgcn_cvt_pkrtz(a, b);
    return __builtin_bit_cast(uint32_t, h);
}

__device__ __forceinline__ float lerp_pk(uint32_t pkv, float wx) {
    h2v h = __builtin_bit_cast(h2v, pkv);
    float a = (float)h[0];
    float b = (float)h[1];
    return fmaf(b - a, wx, a);
}

// ---- kernel 1: bucket + per-entry record ----
__global__ __launch_bounds__(256) void bucket_kernel(
    const float* __restrict__ props, int* __restrict__ wsi, float* __restrict__ wsf)
{
    int b = blockIdx.x;
    __shared__ int counts[63];
    __shared__ int starts[64];
    __shared__ int cursors[63];
    int tid = threadIdx.x;
    if (tid < 63) counts[tid] = 0;
    __syncthreads();
    for (int e = tid; e < NENT; e += 256) {
        int n = e / 7, iz = e - n * 7;
        const float* pr = props + (size_t)(b * N_ + n) * 6;
        float gz = gcoord(pr[2], pr[5], iz);
        int z0 = min(max((int)gz, 0), 62);
        atomicAdd(&counts[z0], 1);
    }
    __syncthreads();
    if (tid == 0) {
        int s = 0;
        for (int k = 0; k < 63; ++k) { starts[k] = s; s += counts[k]; }
        starts[63] = s;
    }
    __syncthreads();
    if (tid < 63) cursors[tid] = starts[tid];
    __syncthreads();
    for (int e = tid; e < NENT; e += 256) {
        int n = e / 7, iz = e - n * 7;
        const float* pr = props + (size_t)(b * N_ + n) * 6;
        float x1p = pr[0], y1p = pr[1], z1p = pr[2];
        float x2p = pr[3], y2p = pr[4], z2p = pr[5];
        float gz = gcoord(z1p, z2p, iz);
        int z0 = min(max((int)gz, 0), 62);
        float wz = gz - (float)z0;
        int pos = atomicAdd(&cursors[z0], 1);
        int off = (b * N_ + n) * (C_ * 343) + iz * 49;
        float* r = wsf + REC_F_BASE + (size_t)(b * NENT + pos) * 8;
        r[0] = x1p; r[1] = (x2p - x1p) * (1.0f / 6.0f);
        r[2] = y1p; r[3] = (y2p - y1p) * (1.0f / 6.0f);
        r[4] = wz;  r[5] = __int_as_float(off);
        r[6] = 0.0f; r[7] = 0.0f;
    }
    if (tid < 64) wsi[b * 64 + tid] = starts[tid];
}

// ---- kernel 2: per-slice streaming, packed-f16 pair slots, 2-deep pipeline ----
__global__ __launch_bounds__(THREADS, 8) void roialign3d_slice_kernel(
    const float* __restrict__ feat,
    const int* __restrict__ wsi,
    const float* __restrict__ wsf,
    float* __restrict__ out)
{
    __shared__ __align__(16) uint32_t pk[4 * PLANE_S];   // 67.6 KB
    __shared__ int ldsStarts[64];

    int s = blockIdx.x;
    int b = s >> 8;
    int c = s & 255;
    const float* vol = feat + (size_t)s * (64 * 64 * 64);
    int tid = threadIdx.x;

    if (tid < 64) ldsStarts[tid] = wsi[b * 64 + tid];
    int swb = (tid >> 4) * SP + ((tid & 15) << 2);       // slot write base (even)

#define STAGE_WRITE(slotBase, v, v4) do {                                   \
        uint2 w0 = make_uint2(pkrtz((v).x, (v).y), pkrtz((v).y, (v).z));    \
        uint2 w1 = make_uint2(pkrtz((v).z, (v).w), pkrtz((v).w, (v4)));     \
        *(uint2*)&pk[(slotBase) + swb]     = w0;                            \
        *(uint2*)&pk[(slotBase) + swb + 2] = w1;                            \
    } while (0)

    // prologue: planes 0,1 -> LDS; planes 2,3 -> register pipeline
    float4 v0     = *(const float4*)(vol + (tid << 2));
    float4 v1     = *(const float4*)(vol + 1 * 4096 + (tid << 2));
    float4 stgOld = *(const float4*)(vol + 2 * 4096 + (tid << 2));  // plane z+2 at z=0
    float4 stgMid = *(const float4*)(vol + 3 * 4096 + (tid << 2));  // plane z+3 at z=0
    {
        float a4 = __shfl_down(v0.x, 1);
        float b4 = __shfl_down(v1.x, 1);
        STAGE_WRITE(0 * PLANE_S, v0, a4);
        STAGE_WRITE(1 * PLANE_S, v1, b4);
    }
    __syncthreads();

    // dense lane map
    int g = tid / 49;
    int p = tid - g * 49;
    int iy = p / 7;
    float fx = (float)(p - iy * 7);
    float fy = (float)iy;
    bool active = (g < GROUPS);

    float* outc = out + (size_t)c * 343;
    const float4* recs = (const float4*)(wsf + REC_F_BASE);
    const int rbase = b * NENT;

    #pragma unroll 1
    for (int z = 0; z < 63; ++z) {
        int aA = (z & 3) * PLANE_S;
        int aB = ((z + 1) & 3) * PLANE_S;
        int aW = ((z + 2) & 3) * PLANE_S;
        float4 stgNew;
        if (z <= 59)
            stgNew = *(const float4*)(vol + (size_t)(z + 4) * 4096 + (tid << 2));

        int base = ldsStarts[z];
        int myCnt = active ? (ldsStarts[z + 1] - base) : 0;
        int roff = rbase + base;

        // ---- 3-stage entry pipeline ----
        int e = g;
        float4 rAn, rBn;                       // record for e+GROUPS
        float wxm, wym, wzm; int offm;         // mid stage (entry e)
        uint32_t q0, q1, q2, q3;
        if (e < myCnt) {
            float4 rAm = recs[(size_t)(roff + e) * 2];
            float4 rBm = recs[(size_t)(roff + e) * 2 + 1];
            if (e + GROUPS < myCnt) {
                rAn = recs[(size_t)(roff + e + GROUPS) * 2];
                rBn = recs[(size_t)(roff + e + GROUPS) * 2 + 1];
            }
            float gx = fmaf(rAm.y, fx, rAm.x);
            float gy = fmaf(rAm.w, fy, rAm.z);
            int x0 = (int)gx, y0 = (int)gy;
            wxm = __builtin_amdgcn_fractf(gx);
            wym = __builtin_amdgcn_fractf(gy);
            wzm = rBm.x; offm = __float_as_int(rBm.y);
            int sl = y0 * SP + x0;
            q0 = pk[aA + sl]; q1 = pk[aA + sl + SP];
            q2 = pk[aB + sl]; q3 = pk[aB + sl + SP];
        }
        while (e < myCnt) {
            int e1 = e + GROUPS;
            int e2 = e1 + GROUPS;
            float wxc = wxm, wyc = wym, wzc = wzm; int offc = offm;
            uint32_t c0 = q0, c1 = q1, c2 = q2, c3 = q3;
            if (e1 < myCnt) {
                float gx = fmaf(rAn.y, fx, rAn.x);
                float gy = fmaf(rAn.w, fy, rAn.z);
                int x0 = (int)gx, y0 = (int)gy;
                wxm = __builtin_amdgcn_fractf(gx);
                wym = __builtin_amdgcn_fractf(gy);
                wzm = rBn.x; offm = __float_as_int(rBn.y);
                int sl = y0 * SP + x0;
                q0 = pk[aA + sl]; q1 = pk[aA + sl + SP];
                q2 = pk[aB + sl]; q3 = pk[aB + sl + SP];
            }
            if (e2 < myCnt) {
                rAn = recs[(size_t)(roff + e2) * 2];
                rBn = recs[(size_t)(roff + e2) * 2 + 1];
            }
            float c00 = lerp_pk(c0, wxc);
            float c01 = lerp_pk(c1, wxc);
            float c10 = lerp_pk(c2, wxc);
            float c11 = lerp_pk(c3, wxc);
            float d0 = fmaf(c01 - c00, wyc, c00);
            float d1 = fmaf(c11 - c10, wyc, c10);
            float r  = fmaf(d1 - d0, wzc, d0);
            __builtin_nontemporal_store(r, &outc[offc + p]);
            e = e1;
        }

        if (z <= 61) {
            float a4 = __shfl_down(stgOld.x, 1);
            STAGE_WRITE(aW, stgOld, a4);   // plane z+2, loaded at step z-2
        }
        __syncthreads();
        stgOld = stgMid;
        stgMid = stgNew;
    }
#undef STAGE_WRITE
}

// ---- fallback (ws too small): round-1 kernel, known correct ----
__global__ __launch_bounds__(128) void roialign3d_fallback(
    const float* __restrict__ feat, const float* __restrict__ props,
    float* __restrict__ out)
{
    int bid = blockIdx.x;
    int xcd = bid & 7;
    int j   = bid >> 3;
    int s   = xcd + ((j >> 9) << 3);
    int n   = j & 511;
    int b   = s >> 8;
    int c   = s & 255;
    const float* prop = props + ((size_t)(b * N_ + n)) * 6;
    float x1p = prop[0], y1p = prop[1], z1p = prop[2];
    float x2p = prop[3], y2p = prop[4], z2p = prop[5];
    float sx = (x2p - x1p) * (1.0f / 6.0f);
    float sy = (y2p - y1p) * (1.0f / 6.0f);
    float sz = (z2p - z1p) * (1.0f / 6.0f);
    const float* vol = feat + (size_t)s * (64 * 64 * 64);
    float* o = out + ((size_t)(b * N_ + n) * C_ + c) * 343;
    for (int p = threadIdx.x; p < 343; p += 128) {
        int iz = p / 49, r = p - iz * 49, iy = r / 7, ix = r - iy * 7;
        float gx = x1p + sx * ix, gy = y1p + sy * iy, gz = z1p + sz * iz;
        int x0 = (int)gx, y0 = (int)gy, z0 = (int)gz;
        float wx = gx - x0, wy = gy - y0, wz = gz - z0;
        int x1 = min(x0 + 1, 63), y1 = min(y0 + 1, 63), z1 = min(z0 + 1, 63);
        const float* p00 = vol + ((z0 * 64 + y0) << 6);
        const float* p01 = vol + ((z0 * 64 + y1) << 6);
        const float* p10 = vol + ((z1 * 64 + y0) << 6);
        const float* p11 = vol + ((z1 * 64 + y1) << 6);
        float c00 = p00[x0] + (p00[x1] - p00[x0]) * wx;
        float c01 = p01[x0] + (p01[x1] - p01[x0]) * wx;
        float c10 = p10[x0] + (p10[x1] - p10[x0]) * wx;
        float c11 = p11[x0] + (p11[x1] - p11[x0]) * wx;
        float d0 = c00 + (c01 - c00) * wy;
        float d1 = c10 + (c11 - c10) * wy;
        o[p] = d0 + (d1 - d0) * wz;
    }
}

extern "C" void kernel_launch(void* const* d_in, const int* in_sizes, int n_in,
                              void* d_out, int out_size, void* d_ws, size_t ws_size,
                              hipStream_t stream) {
    const float* feat  = (const float*)d_in[0];
    const float* props = (const float*)d_in[1];
    float* out = (float*)d_out;

    if (ws_size < WS_NEEDED) {
        roialign3d_fallback<<<B_ * C_ * N_, 128, 0, stream>>>(feat, props, out);
        return;
    }
    int*   wsi = (int*)d_ws;
    float* wsf = (float*)d_ws;
    bucket_kernel<<<B_, 256, 0, stream>>>(props, wsi, wsf);
    roialign3d_slice_kernel<<<B_ * C_, THREADS, 0, stream>>>(feat, wsi, wsf, out);
}

// Round 9
// 299.306 us; speedup vs baseline: 1.2795x; 1.2795x over previous
//
#include <hip/hip_runtime.h>
#include <hip/hip_fp16.h>

// RoIAlign3D: features (B=2, C=256, 64,64,64) f32, proposals (B=2, N=512, 6) f32
// out: (B*N, C, 7, 7, 7) f32
//
// kernel1: bucket 3584 (roi,iz) entries per batch by z0=floor(gz) into CSR +
//   32 B record {x1p,sx,y1p,sy,wz,out_off}.
// kernel2: block = slice (b,c), 1024 thr, 4-plane LDS ring over z.
//   Packed-f16 pair slots: slot(y,x) = {h[x],h[x+1]} -> one b32 read = both
//   x-corners; rows y0/y0+1 merge into ds_read2_b32 (2 LDS instr/point).
//   x-lerp via v_dot2_f32_f16 (f32 accumulate): 4 dot2 + 3 fma per point.
//   Issue order per step: records -> weights -> plane prefetch (sched_barrier
//   pins it) so record waits don't drain the plane load (vmcnt is in-order).
// Coords in [0,63): floor <= 62, +1 <= 63 -> no clamping needed.

#define B_      2
#define C_      256
#define N_      512
#define NENT    (N_ * 7)
#define SP      66                  // slots per row (64 used + 2 pad)
#define PLANE_S (64 * SP)           // 4224 u32 slots per plane
#define THREADS 1024
#define GROUPS  20                  // 20*49 = 980 active lanes
#define REC_F_BASE 128
#define WS_NEEDED ((size_t)REC_F_BASE * 4 + (size_t)B_ * NENT * 8 * 4)

typedef _Float16 h2v __attribute__((ext_vector_type(2)));

__device__ __forceinline__ float gcoord(float lo, float hi, int i) {
    return lo + (hi - lo) * (1.0f / 6.0f) * (float)i;
}

__device__ __forceinline__ uint32_t pkrtz(float a, float b) {
    auto h = __builtin_amdgcn_cvt_pkrtz(a, b);
    return __builtin_bit_cast(uint32_t, h);
}

// (1-wx)*v.lo + wx*v.hi with f32 accumulation
__device__ __forceinline__ float xlerp(uint32_t pkv, uint32_t pkw) {
#if __has_builtin(__builtin_amdgcn_fdot2)
    return __builtin_amdgcn_fdot2(__builtin_bit_cast(h2v, pkv),
                                  __builtin_bit_cast(h2v, pkw), 0.0f, false);
#else
    h2v v = __builtin_bit_cast(h2v, pkv);
    h2v w = __builtin_bit_cast(h2v, pkw);
    return (float)v[0] * (float)w[0] + (float)v[1] * (float)w[1];
#endif
}

// ---- kernel 1: bucket + per-entry record ----
__global__ __launch_bounds__(256) void bucket_kernel(
    const float* __restrict__ props, int* __restrict__ wsi, float* __restrict__ wsf)
{
    int b = blockIdx.x;
    __shared__ int counts[63];
    __shared__ int starts[64];
    __shared__ int cursors[63];
    int tid = threadIdx.x;
    if (tid < 63) counts[tid] = 0;
    __syncthreads();
    for (int e = tid; e < NENT; e += 256) {
        int n = e / 7, iz = e - n * 7;
        const float* pr = props + (size_t)(b * N_ + n) * 6;
        float gz = gcoord(pr[2], pr[5], iz);
        int z0 = min(max((int)gz, 0), 62);
        atomicAdd(&counts[z0], 1);
    }
    __syncthreads();
    if (tid == 0) {
        int s = 0;
        for (int k = 0; k < 63; ++k) { starts[k] = s; s += counts[k]; }
        starts[63] = s;
    }
    __syncthreads();
    if (tid < 63) cursors[tid] = starts[tid];
    __syncthreads();
    for (int e = tid; e < NENT; e += 256) {
        int n = e / 7, iz = e - n * 7;
        const float* pr = props + (size_t)(b * N_ + n) * 6;
        float x1p = pr[0], y1p = pr[1], z1p = pr[2];
        float x2p = pr[3], y2p = pr[4], z2p = pr[5];
        float gz = gcoord(z1p, z2p, iz);
        int z0 = min(max((int)gz, 0), 62);
        float wz = gz - (float)z0;
        int pos = atomicAdd(&cursors[z0], 1);
        int off = (b * N_ + n) * (C_ * 343) + iz * 49;
        float* r = wsf + REC_F_BASE + (size_t)(b * NENT + pos) * 8;
        r[0] = x1p; r[1] = (x2p - x1p) * (1.0f / 6.0f);
        r[2] = y1p; r[3] = (y2p - y1p) * (1.0f / 6.0f);
        r[4] = wz;  r[5] = __int_as_float(off);
        r[6] = 0.0f; r[7] = 0.0f;
    }
    if (tid < 64) wsi[b * 64 + tid] = starts[tid];
}

// ---- kernel 2: per-slice streaming, packed-f16 pair slots ----
__global__ __launch_bounds__(THREADS, 8) void roialign3d_slice_kernel(
    const float* __restrict__ feat,
    const int* __restrict__ wsi,
    const float* __restrict__ wsf,
    float* __restrict__ out)
{
    __shared__ __align__(16) uint32_t pk[4 * PLANE_S];   // 67.6 KB
    __shared__ int ldsStarts[64];

    int s = blockIdx.x;
    int b = s >> 8;
    int c = s & 255;
    const float* vol = feat + (size_t)s * (64 * 64 * 64);
    int tid = threadIdx.x;

    if (tid < 64) ldsStarts[tid] = wsi[b * 64 + tid];
    int swb = (tid >> 4) * SP + ((tid & 15) << 2);       // slot write base (even)

#define STAGE_WRITE(slotBase, v, v4) do {                                   \
        uint2 w0 = make_uint2(pkrtz((v).x, (v).y), pkrtz((v).y, (v).z));    \
        uint2 w1 = make_uint2(pkrtz((v).z, (v).w), pkrtz((v).w, (v4)));     \
        *(uint2*)&pk[(slotBase) + swb]     = w0;                            \
        *(uint2*)&pk[(slotBase) + swb + 2] = w1;                            \
    } while (0)

    // prologue: planes 0,1 -> LDS; plane 2 -> stgA (written at end of z=0)
    float4 v0   = *(const float4*)(vol + (tid << 2));
    float4 v1   = *(const float4*)(vol + 1 * 4096 + (tid << 2));
    float4 stgA = *(const float4*)(vol + 2 * 4096 + (tid << 2));
    {
        float a4 = __shfl_down(v0.x, 1);
        float b4 = __shfl_down(v1.x, 1);
        STAGE_WRITE(0 * PLANE_S, v0, a4);
        STAGE_WRITE(1 * PLANE_S, v1, b4);
    }
    __syncthreads();

    // dense lane map
    int g = tid / 49;
    int p = tid - g * 49;
    int iy = p / 7;
    float fx = (float)(p - iy * 7);
    float fy = (float)iy;
    bool active = (g < GROUPS);

    float* outc = out + (size_t)c * 343;
    const float4* recs = (const float4*)(wsf + REC_F_BASE);
    const int rbase = b * NENT;

    #pragma unroll 1
    for (int z = 0; z < 63; ++z) {
        int aA = (z & 3) * PLANE_S;
        int aB = ((z + 1) & 3) * PLANE_S;
        int aW = ((z + 2) & 3) * PLANE_S;

        int base = ldsStarts[z];
        int myCnt = active ? (ldsStarts[z + 1] - base) : 0;
        int roff = rbase + base;

        // --- records FIRST (their waits must not drain the plane load) ---
        int e = g;
        float4 rAn, rBn;                       // record for e+GROUPS
        uint32_t pw, q0, q1, q2, q3;
        float wym, wzm; int offm;
        if (e < myCnt) {
            float4 rA1 = recs[(size_t)(roff + e) * 2];
            float4 rB1 = recs[(size_t)(roff + e) * 2 + 1];
            if (e + GROUPS < myCnt) {
                rAn = recs[(size_t)(roff + e + GROUPS) * 2];
                rBn = recs[(size_t)(roff + e + GROUPS) * 2 + 1];
            }
            float gx = fmaf(rA1.y, fx, rA1.x);
            float gy = fmaf(rA1.w, fy, rA1.z);
            int x0 = (int)gx, y0 = (int)gy;
            float wx = __builtin_amdgcn_fractf(gx);
            wym = __builtin_amdgcn_fractf(gy);
            pw = pkrtz(1.0f - wx, wx);
            wzm = rB1.x; offm = __float_as_int(rB1.y);
            int sl = y0 * SP + x0;
            q0 = pk[aA + sl]; q1 = pk[aA + sl + SP];
            q2 = pk[aB + sl]; q3 = pk[aB + sl + SP];
        }
        __builtin_amdgcn_sched_barrier(0);
        // --- plane prefetch (z+3), issued after all prologue record loads ---
        float4 stgB;
        if (z <= 60)
            stgB = *(const float4*)(vol + (size_t)(z + 3) * 4096 + (tid << 2));

        while (e < myCnt) {
            int e1 = e + GROUPS;
            int e2 = e1 + GROUPS;
            uint32_t pwc = pw, c0 = q0, c1 = q1, c2 = q2, c3 = q3;
            float wyc = wym, wzc = wzm; int offc = offm;
            if (e1 < myCnt) {
                float gx = fmaf(rAn.y, fx, rAn.x);
                float gy = fmaf(rAn.w, fy, rAn.z);
                int x0 = (int)gx, y0 = (int)gy;
                float wx = __builtin_amdgcn_fractf(gx);
                wym = __builtin_amdgcn_fractf(gy);
                pw = pkrtz(1.0f - wx, wx);
                wzm = rBn.x; offm = __float_as_int(rBn.y);
                int sl = y0 * SP + x0;
                q0 = pk[aA + sl]; q1 = pk[aA + sl + SP];
                q2 = pk[aB + sl]; q3 = pk[aB + sl + SP];
            }
            if (e2 < myCnt) {
                rAn = recs[(size_t)(roff + e2) * 2];
                rBn = recs[(size_t)(roff + e2) * 2 + 1];
            }
            float c00 = xlerp(c0, pwc);
            float c01 = xlerp(c1, pwc);
            float c10 = xlerp(c2, pwc);
            float c11 = xlerp(c3, pwc);
            float d0 = fmaf(c01 - c00, wyc, c00);
            float d1 = fmaf(c11 - c10, wyc, c10);
            outc[offc + p] = fmaf(d1 - d0, wzc, d0);
            e = e1;
        }

        if (z <= 61) {
            float a4 = __shfl_down(stgA.x, 1);
            STAGE_WRITE(aW, stgA, a4);   // plane z+2, loaded at step z-1
        }
        __syncthreads();
        stgA = stgB;
    }
#undef STAGE_WRITE
}

// ---- fallback (ws too small): round-1 kernel, known correct ----
__global__ __launch_bounds__(128) void roialign3d_fallback(
    const float* __restrict__ feat, const float* __restrict__ props,
    float* __restrict__ out)
{
    int bid = blockIdx.x;
    int xcd = bid & 7;
    int j   = bid >> 3;
    int s   = xcd + ((j >> 9) << 3);
    int n   = j & 511;
    int b   = s >> 8;
    int c   = s & 255;
    const float* prop = props + ((size_t)(b * N_ + n)) * 6;
    float x1p = prop[0], y1p = prop[1], z1p = prop[2];
    float x2p = prop[3], y2p = prop[4], z2p = prop[5];
    float sx = (x2p - x1p) * (1.0f / 6.0f);
    float sy = (y2p - y1p) * (1.0f / 6.0f);
    float sz = (z2p - z1p) * (1.0f / 6.0f);
    const float* vol = feat + (size_t)s * (64 * 64 * 64);
    float* o = out + ((size_t)(b * N_ + n) * C_ + c) * 343;
    for (int p = threadIdx.x; p < 343; p += 128) {
        int iz = p / 49, r = p - iz * 49, iy = r / 7, ix = r - iy * 7;
        float gx = x1p + sx * ix, gy = y1p + sy * iy, gz = z1p + sz * iz;
        int x0 = (int)gx, y0 = (int)gy, z0 = (int)gz;
        float wx = gx - x0, wy = gy - y0, wz = gz - z0;
        int x1 = min(x0 + 1, 63), y1 = min(y0 + 1, 63), z1 = min(z0 + 1, 63);
        const float* p00 = vol + ((z0 * 64 + y0) << 6);
        const float* p01 = vol + ((z0 * 64 + y1) << 6);
        const float* p10 = vol + ((z1 * 64 + y0) << 6);
        const float* p11 = vol + ((z1 * 64 + y1) << 6);
        float c00 = p00[x0] + (p00[x1] - p00[x0]) * wx;
        float c01 = p01[x0] + (p01[x1] - p01[x0]) * wx;
        float c10 = p10[x0] + (p10[x1] - p10[x0]) * wx;
        float c11 = p11[x0] + (p11[x1] - p11[x0]) * wx;
        float d0 = c00 + (c01 - c00) * wy;
        float d1 = c10 + (c11 - c10) * wy;
        o[p] = d0 + (d1 - d0) * wz;
    }
}

extern "C" void kernel_launch(void* const* d_in, const int* in_sizes, int n_in,
                              void* d_out, int out_size, void* d_ws, size_t ws_size,
                              hipStream_t stream) {
    const float* feat  = (const float*)d_in[0];
    const float* props = (const float*)d_in[1];
    float* out = (float*)d_out;

    if (ws_size < WS_NEEDED) {
        roialign3d_fallback<<<B_ * C_ * N_, 128, 0, stream>>>(feat, props, out);
        return;
    }
    int*   wsi = (int*)d_ws;
    float* wsf = (float*)d_ws;
    bucket_kernel<<<B_, 256, 0, stream>>>(props, wsi, wsf);
    roialign3d_slice_kernel<<<B_ * C_, THREADS, 0, stream>>>(feat, wsi, wsf, out);
}

// Round 10
// 290.396 us; speedup vs baseline: 1.3188x; 1.0307x over previous
//
#include <hip/hip_runtime.h>
#include <hip/hip_fp16.h>

// RoIAlign3D: features (B=2, C=256, 64,64,64) f32, proposals (B=2, N=512, 6) f32
// out: (B*N, C, 7, 7, 7) f32
//
// kernel1: bucket 3584 (roi,iz) entries per batch by z0=floor(gz) into CSR +
//   32 B record {x1p,sx,y1p,sy, wz,out_off,z0,-}.
// kernel2: block = (slice, z-chunk of 3 z0s). Stage 4 planes (f16-pair slots)
//   with 16 in-flight float4 loads, ONE barrier, then process the chunk's
//   CSR-contiguous entries with zero further syncs. 2 blocks/CU -> staging
//   of one block overlaps compute of the other. No per-z ring, no 63-step
//   barrier chain (that chain was the ~300us floor in rounds 6-9).
// Packed-f16 pair slots: slot(y,x)={h[x],h[x+1]} -> 1 b32 read = both
//   x-corners; y0/y0+1 rows merge to ds_read2_b32.
// Coords in [0,63): floor<=62, +1<=63 -> no clamping needed.

#define B_      2
#define C_      256
#define N_      512
#define NENT    (N_ * 7)
#define SP      66                  // slots per row (64 used + 2 pad)
#define PLANE_S (64 * SP)           // 4224 u32 slots per plane
#define CHUNK   3                   // z0 values per block
#define NCHUNK  21                  // 63 / 3
#define THREADS 1024
#define GROUPS  20                  // 20*49 = 980 active lanes
#define REC_F_BASE 128
#define WS_NEEDED ((size_t)REC_F_BASE * 4 + (size_t)B_ * NENT * 8 * 4)

typedef _Float16 h2v __attribute__((ext_vector_type(2)));

__device__ __forceinline__ float gcoord(float lo, float hi, int i) {
    return lo + (hi - lo) * (1.0f / 6.0f) * (float)i;
}

__device__ __forceinline__ uint32_t pkrtz(float a, float b) {
    auto h = __builtin_amdgcn_cvt_pkrtz(a, b);
    return __builtin_bit_cast(uint32_t, h);
}

// (1-wx)*v.lo + wx*v.hi with f32 accumulation
__device__ __forceinline__ float xlerp(uint32_t pkv, uint32_t pkw) {
#if __has_builtin(__builtin_amdgcn_fdot2)
    return __builtin_amdgcn_fdot2(__builtin_bit_cast(h2v, pkv),
                                  __builtin_bit_cast(h2v, pkw), 0.0f, false);
#else
    h2v v = __builtin_bit_cast(h2v, pkv);
    h2v w = __builtin_bit_cast(h2v, pkw);
    return (float)v[0] * (float)w[0] + (float)v[1] * (float)w[1];
#endif
}

// ---- kernel 1: bucket + per-entry record ----
__global__ __launch_bounds__(256) void bucket_kernel(
    const float* __restrict__ props, int* __restrict__ wsi, float* __restrict__ wsf)
{
    int b = blockIdx.x;
    __shared__ int counts[63];
    __shared__ int starts[64];
    __shared__ int cursors[63];
    int tid = threadIdx.x;
    if (tid < 63) counts[tid] = 0;
    __syncthreads();
    for (int e = tid; e < NENT; e += 256) {
        int n = e / 7, iz = e - n * 7;
        const float* pr = props + (size_t)(b * N_ + n) * 6;
        float gz = gcoord(pr[2], pr[5], iz);
        int z0 = min(max((int)gz, 0), 62);
        atomicAdd(&counts[z0], 1);
    }
    __syncthreads();
    if (tid == 0) {
        int s = 0;
        for (int k = 0; k < 63; ++k) { starts[k] = s; s += counts[k]; }
        starts[63] = s;
    }
    __syncthreads();
    if (tid < 63) cursors[tid] = starts[tid];
    __syncthreads();
    for (int e = tid; e < NENT; e += 256) {
        int n = e / 7, iz = e - n * 7;
        const float* pr = props + (size_t)(b * N_ + n) * 6;
        float x1p = pr[0], y1p = pr[1], z1p = pr[2];
        float x2p = pr[3], y2p = pr[4], z2p = pr[5];
        float gz = gcoord(z1p, z2p, iz);
        int z0 = min(max((int)gz, 0), 62);
        float wz = gz - (float)z0;
        int pos = atomicAdd(&cursors[z0], 1);
        int off = (b * N_ + n) * (C_ * 343) + iz * 49;
        float* r = wsf + REC_F_BASE + (size_t)(b * NENT + pos) * 8;
        r[0] = x1p; r[1] = (x2p - x1p) * (1.0f / 6.0f);
        r[2] = y1p; r[3] = (y2p - y1p) * (1.0f / 6.0f);
        r[4] = wz;  r[5] = __int_as_float(off);
        r[6] = __int_as_float(z0); r[7] = 0.0f;
    }
    if (tid < 64) wsi[b * 64 + tid] = starts[tid];
}

// ---- kernel 2: one block = (slice, 3-z0 chunk); stage 4 planes, no ring ----
__global__ __launch_bounds__(THREADS, 8) void roialign3d_chunk_kernel(
    const float* __restrict__ feat,
    const int* __restrict__ wsi,
    const float* __restrict__ wsf,
    float* __restrict__ out)
{
    __shared__ __align__(16) uint32_t pk[4 * PLANE_S];   // 67.6 KB

    int bid = blockIdx.x;
    int s = bid & 511;          // slice = b*C + c (slice-fastest: 512 blocks of
    int k = bid >> 9;           // one chunk-wave in flight -> records L2-hot)
    int b = s >> 8;
    int c = s & 255;
    int zlo = k * CHUNK;
    const float* vol = feat + (size_t)s * 262144 + (size_t)zlo * 4096;
    int tid = threadIdx.x;

    // chunk CSR bounds (block-uniform scalar loads)
    int base = wsi[b * 64 + zlo];
    int end  = wsi[b * 64 + zlo + CHUNK];

    // ---- stage: issue all 4 plane loads (64 KB in flight) ----
    float4 v0 = *(const float4*)(vol + 0 * 4096 + (tid << 2));
    float4 v1 = *(const float4*)(vol + 1 * 4096 + (tid << 2));
    float4 v2 = *(const float4*)(vol + 2 * 4096 + (tid << 2));
    float4 v3 = *(const float4*)(vol + 3 * 4096 + (tid << 2));

    // dense lane map + first record prefetch (in flight behind plane loads)
    int g = tid / 49;
    int p = tid - g * 49;
    int iy = p / 7;
    float fx = (float)(p - iy * 7);
    float fy = (float)iy;
    const float4* recs = (const float4*)(wsf + REC_F_BASE);
    const int rbase = b * NENT;
    int myEnd = (g < GROUPS) ? end : base;    // inactive groups: no iterations
    int e = base + g;
    float4 rA, rB, rAn, rBn;
    if (e < myEnd) {
        rA = recs[(size_t)(rbase + e) * 2];
        rB = recs[(size_t)(rbase + e) * 2 + 1];
        if (e + GROUPS < myEnd) {
            rAn = recs[(size_t)(rbase + e + GROUPS) * 2];
            rBn = recs[(size_t)(rbase + e + GROUPS) * 2 + 1];
        }
    }

    int swb = (tid >> 4) * SP + ((tid & 15) << 2);
#define STAGE_WRITE(slotBase, v, v4) do {                                   \
        uint2 w0 = make_uint2(pkrtz((v).x, (v).y), pkrtz((v).y, (v).z));    \
        uint2 w1 = make_uint2(pkrtz((v).z, (v).w), pkrtz((v).w, (v4)));     \
        *(uint2*)&pk[(slotBase) + swb]     = w0;                            \
        *(uint2*)&pk[(slotBase) + swb + 2] = w1;                            \
    } while (0)
    {
        float a0 = __shfl_down(v0.x, 1);
        float a1 = __shfl_down(v1.x, 1);
        float a2 = __shfl_down(v2.x, 1);
        float a3 = __shfl_down(v3.x, 1);
        STAGE_WRITE(0 * PLANE_S, v0, a0);
        STAGE_WRITE(1 * PLANE_S, v1, a1);
        STAGE_WRITE(2 * PLANE_S, v2, a2);
        STAGE_WRITE(3 * PLANE_S, v3, a3);
    }
#undef STAGE_WRITE
    __syncthreads();

    // ---- entry loop: no barriers, ~ceil(cnt/20) passes ----
    float* outc = out + (size_t)c * 343;
    while (e < myEnd) {
        float gx = fmaf(rA.y, fx, rA.x);
        float gy = fmaf(rA.w, fy, rA.z);
        int x0 = (int)gx, y0 = (int)gy;
        float wx = __builtin_amdgcn_fractf(gx);
        float wy = __builtin_amdgcn_fractf(gy);
        uint32_t pw = pkrtz(1.0f - wx, wx);
        float wz = rB.x;
        int offc = __float_as_int(rB.y);
        int lz = __float_as_int(rB.z) - zlo;           // 0..2
        int sl = lz * PLANE_S + y0 * SP + x0;
        uint32_t q0 = pk[sl],           q1 = pk[sl + SP];
        uint32_t q2 = pk[sl + PLANE_S], q3 = pk[sl + PLANE_S + SP];

        // rotate record pipeline; prefetch e+2*GROUPS
        float4 tA = rAn, tB = rBn;
        int e2 = e + 2 * GROUPS;
        if (e2 < myEnd) {
            rAn = recs[(size_t)(rbase + e2) * 2];
            rBn = recs[(size_t)(rbase + e2) * 2 + 1];
        }

        float c00 = xlerp(q0, pw);
        float c01 = xlerp(q1, pw);
        float c10 = xlerp(q2, pw);
        float c11 = xlerp(q3, pw);
        float d0 = fmaf(c01 - c00, wy, c00);
        float d1 = fmaf(c11 - c10, wy, c10);
        outc[offc + p] = fmaf(d1 - d0, wz, d0);

        e += GROUPS; rA = tA; rB = tB;
    }
}

// ---- fallback (ws too small): round-1 kernel, known correct ----
__global__ __launch_bounds__(128) void roialign3d_fallback(
    const float* __restrict__ feat, const float* __restrict__ props,
    float* __restrict__ out)
{
    int bid = blockIdx.x;
    int xcd = bid & 7;
    int j   = bid >> 3;
    int s   = xcd + ((j >> 9) << 3);
    int n   = j & 511;
    int b   = s >> 8;
    int c   = s & 255;
    const float* prop = props + ((size_t)(b * N_ + n)) * 6;
    float x1p = prop[0], y1p = prop[1], z1p = prop[2];
    float x2p = prop[3], y2p = prop[4], z2p = prop[5];
    float sx = (x2p - x1p) * (1.0f / 6.0f);
    float sy = (y2p - y1p) * (1.0f / 6.0f);
    float sz = (z2p - z1p) * (1.0f / 6.0f);
    const float* vol = feat + (size_t)s * (64 * 64 * 64);
    float* o = out + ((size_t)(b * N_ + n) * C_ + c) * 343;
    for (int p = threadIdx.x; p < 343; p += 128) {
        int iz = p / 49, r = p - iz * 49, iy = r / 7, ix = r - iy * 7;
        float gx = x1p + sx * ix, gy = y1p + sy * iy, gz = z1p + sz * iz;
        int x0 = (int)gx, y0 = (int)gy, z0 = (int)gz;
        float wx = gx - x0, wy = gy - y0, wz = gz - z0;
        int x1 = min(x0 + 1, 63), y1 = min(y0 + 1, 63), z1 = min(z0 + 1, 63);
        const float* p00 = vol + ((z0 * 64 + y0) << 6);
        const float* p01 = vol + ((z0 * 64 + y1) << 6);
        const float* p10 = vol + ((z1 * 64 + y0) << 6);
        const float* p11 = vol + ((z1 * 64 + y1) << 6);
        float c00 = p00[x0] + (p00[x1] - p00[x0]) * wx;
        float c01 = p01[x0] + (p01[x1] - p01[x0]) * wx;
        float c10 = p10[x0] + (p10[x1] - p10[x0]) * wx;
        float c11 = p11[x0] + (p11[x1] - p11[x0]) * wx;
        float d0 = c00 + (c01 - c00) * wy;
        float d1 = c10 + (c11 - c10) * wy;
        o[p] = d0 + (d1 - d0) * wz;
    }
}

extern "C" void kernel_launch(void* const* d_in, const int* in_sizes, int n_in,
                              void* d_out, int out_size, void* d_ws, size_t ws_size,
                              hipStream_t stream) {
    const float* feat  = (const float*)d_in[0];
    const float* props = (const float*)d_in[1];
    float* out = (float*)d_out;

    if (ws_size < WS_NEEDED) {
        roialign3d_fallback<<<B_ * C_ * N_, 128, 0, stream>>>(feat, props, out);
        return;
    }
    int*   wsi = (int*)d_ws;
    float* wsf = (float*)d_ws;
    bucket_kernel<<<B_, 256, 0, stream>>>(props, wsi, wsf);
    roialign3d_chunk_kernel<<<NCHUNK * 512, THREADS, 0, stream>>>(feat, wsi, wsf, out);
}